// Round 1
// 170.090 us; speedup vs baseline: 1.0337x; 1.0337x over previous
//
#include <hip/hip_runtime.h>

#define IMG 512
#define HALO 5
#define BAND 16
#define NB 8           // bands per block (128 rows / 16)
#define RING 26        // ring slots == live rows (16 + 2*5)

// Gaussian window, sigma=1.5, ws=11, normalized (matches reference _make_window)
#define W0 1.0283800e-03f
#define W1 7.5987582e-03f
#define W2 3.6000773e-02f
#define W3 1.0936070e-01f
#define W4 2.1300553e-01f
#define W5 2.6601172e-01f

typedef float f2 __attribute__((ext_vector_type(2)));

__device__ __forceinline__ f2 pkfma(f2 a, f2 b, f2 c) {
    return __builtin_elementwise_fma(a, b, c);   // -> v_pk_fma_f32
}

// Raw workgroup barrier: drain LDS only, leave global loads in flight.
#define LGKM_BARRIER() asm volatile("s_waitcnt lgkmcnt(0)\n\ts_barrier" ::: "memory")

__global__ __launch_bounds__(256, 5)
void ssim_main(const float* __restrict__ img1, const float* __restrict__ img2,
               float* __restrict__ part)
{
    const float Wt[11] = {W0,W1,W2,W3,W4,W5,W4,W3,W2,W1,W0};
    constexpr float C1 = 1.0e-4f;
    constexpr float C2 = 9.0e-4f;

    // Ring of horizontal-blur results, 4 fused channels per px:
    //   (bx = h-blur(x), by = h-blur(y), bs = h-blur(x^2+y^2), bp = h-blur(x*y))
    // Physical column is XOR-swizzled: phys = c ^ (c>>2). Bijective, keeps the
    // vertical read (col = lane) a full-bank permutation AND spreads the
    // 4-consecutive-float4 write pattern across all bank-start classes.
    __shared__ float4 sH[RING][64];      // 26624 B -> 6 blocks/CU LDS-wise
    __shared__ float  sRed[4];

    const int bx      = blockIdx.x;
    const int n       = bx >> 5;          // image 0..63
    const int stripe  = (bx >> 2) & 7;    // 64-col stripe
    const int quarter = bx & 3;           // 128-row quarter
    const int gx0     = stripe << 6;
    const int base    = quarter << 7;
    const int tid     = threadIdx.x;
    const bool edge   = (stripe == 0) | (stripe == 7);

    const float* __restrict__ base1 = img1 + (size_t)n * IMG * IMG;
    const float* __restrict__ base2 = img2 + (size_t)n * IMG * IMG;

    float acc = 0.0f;

    // ---- predicated 20-col window load (5 aligned float4 per image)
    auto loadRowP = [&](const float* r1, const float* r2, bool rok, int gcb,
                        float4* px, float4* py) {
        #pragma unroll
        for (int t = 0; t < 5; ++t) {
            int gc = gcb - 8 + (t << 2);
            bool ok = rok && (gc >= 0) && (gc < IMG);
            px[t] = ok ? ((const float4*)r1)[t] : make_float4(0.f,0.f,0.f,0.f);
            py[t] = ok ? ((const float4*)r2)[t] : make_float4(0.f,0.f,0.f,0.f);
        }
    };

    // ---- horizontal blur of a preloaded row -> ring[slot], 4 output cols.
    // Accumulate-by-input-index: each input element is consumed by its <=4
    // taps immediately and dies -> minimal live set, nothing to recompute.
    auto horizStore = [&](const float4* px, const float4* py, int slot, int cg) {
        f2 m[4]  = {f2{0.f,0.f},f2{0.f,0.f},f2{0.f,0.f},f2{0.f,0.f}};
        f2 t2[4] = {f2{0.f,0.f},f2{0.f,0.f},f2{0.f,0.f},f2{0.f,0.f}};
        #pragma unroll
        for (int t = 0; t < 5; ++t) {
            #pragma unroll
            for (int e = 0; e < 4; ++e) {
                const int j = (t << 2) + e;          // 0..19, taps use 3..16
                if (j < 3 || j > 16) continue;
                const float x = (e==0) ? px[t].x : (e==1) ? px[t].y : (e==2) ? px[t].z : px[t].w;
                const float y = (e==0) ? py[t].x : (e==1) ? py[t].y : (e==2) ? py[t].z : py[t].w;
                const f2 v  = {x, y};
                const f2 s2 = {fmaf(x, x, y*y), x*y};
                #pragma unroll
                for (int o = 0; o < 4; ++o) {
                    const int k = j - 3 - o;         // tap index for output o
                    if (0 <= k && k <= 10) {
                        const f2 w = {Wt[k], Wt[k]};
                        m[o]  = pkfma(w, v,  m[o]);
                        t2[o] = pkfma(w, s2, t2[o]);
                    }
                }
            }
        }
        const int c4 = cg << 2;
        #pragma unroll
        for (int o = 0; o < 4; ++o) {
            const int wc = (c4 + o) ^ cg;            // phys col = c ^ (c>>2)
            sH[slot][wc] = make_float4(m[o].x, m[o].y, t2[o].x, t2[o].y);
        }
    };

    // ---- prologue: h-blur rows base-5 .. base+20 into slots 0..25 (no mod)
    for (int task = tid; task < RING * 16; task += 256) {
        const int i   = task >> 4;                   // 0..25 == slot
        const int cg  = task & 15;
        const int gr  = base - HALO + i;             // max 384+20 < 512 always
        const int gcb = gx0 + (cg << 2);
        const float* r1 = base1 + (ptrdiff_t)gr * IMG + gcb - 8;
        const float* r2 = base2 + (ptrdiff_t)gr * IMG + gcb - 8;
        float4 px[5], py[5];
        if (!edge && gr >= 0) {
            #pragma unroll
            for (int t = 0; t < 5; ++t) {
                px[t] = ((const float4*)r1)[t];
                py[t] = ((const float4*)r2)[t];
            }
        } else {
            loadRowP(r1, r2, gr >= 0, gcb, px, py);
        }
        horizStore(px, py, i, cg);
    }

    // ---- steady-state pointers: this thread's prefetch row for band b is
    //      base + 16b + 21 + rr at cols gcb-8 .. gcb+11
    const int rr  = tid >> 4;                        // 0..15
    const int cgs = tid & 15;
    const int gcb = gx0 + (cgs << 2);
    const float* p1 = base1 + (ptrdiff_t)(base + 21 + rr) * IMG + gcb - 8;
    const float* p2 = base2 + (ptrdiff_t)(base + 21 + rr) * IMG + gcb - 8;

    const int col  = tid & 63;
    const int rcol = col ^ (col >> 2);               // phys read col
    const int wv   = __builtin_amdgcn_readfirstlane(tid >> 6);

    int sb = 0;                                      // (16*b) mod RING, scalar
    for (int b = 0; b < NB; ++b) {
        float4 px[5], py[5];
        const bool pf = (b + 1 < NB);
        if (pf) {
            // rows OOB only possible when quarter==3 && b==NB-2 (501..516)
            const bool rowsafe = (quarter < 3) | (b < NB - 2);
            if (rowsafe & (!edge)) {
                #pragma unroll
                for (int t = 0; t < 5; ++t) {
                    px[t] = ((const float4*)p1)[t];
                    py[t] = ((const float4*)p2)[t];
                }
            } else {
                const int gr = base + (b << 4) + 21 + rr;
                loadRowP(p1, p2, (unsigned)gr < (unsigned)IMG, gcb, px, py);
            }
        }

        LGKM_BARRIER();                              // ring rows for this band ready

        // ---- vertical blur + SSIM: 4 rows/thread, accumulate-by-input-row
        {
            const int d0 = sb + (wv << 2);           // uniform, <= 37
            f2 ma[4] = {f2{0.f,0.f},f2{0.f,0.f},f2{0.f,0.f},f2{0.f,0.f}};
            f2 sa[4] = {f2{0.f,0.f},f2{0.f,0.f},f2{0.f,0.f},f2{0.f,0.f}};
            #pragma unroll
            for (int i = 0; i < 14; ++i) {
                int s = d0 + i;                      // <= 50 -> one cond sub
                s -= (s >= RING) ? RING : 0;
                const float4 q = sH[s][rcol];
                const f2 v = {q.x, q.y};             // (bx, by)
                const f2 u = {q.z, q.w};             // (bs, bp)
                #pragma unroll
                for (int o = 0; o < 4; ++o) {
                    const int k = i - o;             // tap index for row o
                    if (0 <= k && k <= 10) {
                        const f2 w = {Wt[k], Wt[k]};
                        ma[o] = pkfma(w, v, ma[o]);
                        sa[o] = pkfma(w, u, sa[o]);
                    }
                }
            }
            #pragma unroll
            for (int o = 0; o < 4; ++o) {
                const f2 m   = ma[o];
                const f2 tt  = sa[o];
                const f2 msq = m * m;                // (mu1^2, mu2^2)
                const float mu12  = m.x * m.y;
                const float musum = msq.x + msq.y;
                const float g12 = tt.y - mu12;       // sigma12
                const float gs  = tt.x - musum;      // sigma1^2 + sigma2^2
                const float num = fmaf(2.f, mu12, C1) * fmaf(2.f, g12, C2);
                const float den = (musum + C1) * (gs + C2);
                acc = fmaf(num, __builtin_amdgcn_rcpf(den), acc);
            }
        }

        LGKM_BARRIER();                              // vert reads done (WAR on ring)

        if (pf) {
            int t = sb + rr;                         // (sb+26+rr) mod 26, <= 40
            t -= (t >= RING) ? RING : 0;
            horizStore(px, py, t, cgs);
            p1 += BAND * IMG;
            p2 += BAND * IMG;
        }
        sb += BAND;
        sb -= (sb >= RING) ? RING : 0;
    }

    // ---- block reduction -> one partial per block
    #pragma unroll
    for (int off = 32; off > 0; off >>= 1)
        acc += __shfl_down(acc, off, 64);
    if ((tid & 63) == 0) sRed[tid >> 6] = acc;
    LGKM_BARRIER();
    if (tid == 0) part[bx] = sRed[0] + sRed[1] + sRed[2] + sRed[3];
}

__global__ void ssim_finalize(const float* __restrict__ part, float* __restrict__ out)
{
    __shared__ double sD[4];
    double s = 0.0;
    const int t = threadIdx.x;
    for (int i = t; i < 2048; i += 256) s += (double)part[i];
    #pragma unroll
    for (int off = 32; off > 0; off >>= 1)
        s += __shfl_down(s, off, 64);
    if ((t & 63) == 0) sD[t >> 6] = s;
    __syncthreads();
    if (t == 0) out[0] = (float)((sD[0] + sD[1] + sD[2] + sD[3]) * (1.0 / 16777216.0));
}

extern "C" void kernel_launch(void* const* d_in, const int* in_sizes, int n_in,
                              void* d_out, int out_size, void* d_ws, size_t ws_size,
                              hipStream_t stream)
{
    const float* img1 = (const float*)d_in[0];
    const float* img2 = (const float*)d_in[1];
    float* out  = (float*)d_out;
    float* part = (float*)d_ws;      // 2048 floats of scratch

    ssim_main<<<2048, 256, 0, stream>>>(img1, img2, part);
    ssim_finalize<<<1, 256, 0, stream>>>(part, out);
}